// Round 15
// baseline (298.875 us; speedup 1.0000x reference)
//
#include <hip/hip_runtime.h>
#include <stdint.h>

typedef __bf16 bf16;
typedef __attribute__((ext_vector_type(4))) float f4;
typedef __attribute__((ext_vector_type(4))) float f32x4;
typedef __attribute__((ext_vector_type(8))) __bf16 bf8v;
typedef __attribute__((ext_vector_type(4))) __bf16 bf4v;

#define NN 30000
#define MPAD 30080
#define OUTSTRIDE 15360000     // 30000*512
#define XB 7500                // cast blocks in k_xp (1920000/256)
#define SC_B 1875              // scatter blocks in k_fused (480000/256)
#define TWO32 4294967296.0
#define ZN16 15004             // 240064 bytes / 16 (degcnt + gctr)

typedef __attribute__((address_space(3))) unsigned int as3_u32;
typedef __attribute__((address_space(1))) unsigned int as1_u32;

__device__ __forceinline__ void gl_lds16(const void* g, void* l) {
  __builtin_amdgcn_global_load_lds((as1_u32*)g, (as3_u32*)l, 16, 0, 0);
}

// ---------- zero {degcnt, gctr} ----------
__global__ void k_zero(f4* __restrict__ p) {
  int i = blockIdx.x * 256 + threadIdx.x;
  if (i < ZN16) { f4 z = {0.f, 0.f, 0.f, 0.f}; p[i] = z; }
}

// ---------- fused: x->bf16 cast + per-edge degree/count accumulation ----------
// degcnt[d] (double) accumulates ew + 2^32 (count in upper bits, weight-sum in lower).
__global__ void k_xp(const float* __restrict__ x, bf16* __restrict__ xbf,
                     const int* __restrict__ ei, const float* __restrict__ ew,
                     double* __restrict__ degcnt, int E) {
  int b = blockIdx.x;
  if (b < XB) {
    int i = b * 256 + threadIdx.x;
    const f4* x4 = (const f4*)x;
    f4 a = x4[2 * i], c = x4[2 * i + 1];
    bf8v o;
#pragma unroll
    for (int j = 0; j < 4; ++j) { o[j] = (bf16)a[j]; o[4 + j] = (bf16)c[j]; }
    ((bf8v*)xbf)[i] = o;
  } else {
    int e = (b - XB) * 256 + threadIdx.x;
    if (e < E) {
      int d = ei[E + e];
      atomicAdd(&degcnt[d], (double)ew[e] + TWO32);
    }
  }
}

// ---------- dinv + atomic CSR offset allocation; curs pre-set to start ----------
__global__ void k_doffs(const double* __restrict__ degcnt, float* __restrict__ dinv,
                        int* __restrict__ gctr, int* __restrict__ curs,
                        int2* __restrict__ off2, int n) {
  int i = blockIdx.x * 256 + threadIdx.x;
  if (i >= n) return;
  double v = degcnt[i];
  double c = (double)(long long)(v * (1.0 / TWO32));  // exact count
  int cnt = (int)c;
  float deg = (float)(v - c * TWO32);
  dinv[i] = rsqrtf(deg + 1.0f);  // +1 = self-loop weight
  int start = atomicAdd(gctr, cnt);
  curs[i] = start;                    // scatter cursor starts at segment base
  off2[i] = make_int2(start, start + cnt);
}

// ---------- fused: scatter (CSR build, cursor-only) + W_comb (64j x 32k) + bias ----------
__global__ void k_fused(const int* __restrict__ ei, const float* __restrict__ ew,
                        const float* __restrict__ dinv,
                        int* __restrict__ cursor, int2* __restrict__ sn, int E,
                        const float* __restrict__ WcA, const float* __restrict__ WlA,
                        const float* __restrict__ WcB, const float* __restrict__ WlB,
                        const float* __restrict__ WcC, const float* __restrict__ WlC,
                        bf16* __restrict__ Wt,
                        const float* __restrict__ bcA, const float* __restrict__ blA,
                        const float* __restrict__ bcB, const float* __restrict__ blB,
                        const float* __restrict__ bcC, const float* __restrict__ blC,
                        float* __restrict__ bcomb) {
  __shared__ float sWc[32][17];   // [k][c] chunk
  __shared__ float sWl[16][64];   // [c][j] chunk
  __shared__ float smr[4][64];
  int b = blockIdx.x;
  if (b < SC_B) {
    // -------- scatter edges into CSR-by-dst (packed {src, norm}) --------
    int e = b * 256 + threadIdx.x;
    if (e >= E) return;
    int s = ei[e], d = ei[E + e];
    int pos = atomicAdd(&cursor[d], 1);
    sn[pos] = make_int2(s, __float_as_int(dinv[s] * ew[e] * dinv[d]));
  } else if (b < SC_B + 384) {
    // -------- Wt[g][j][k] = sum_c Wc_g[k][c] * Wl_g[c][j], 64j x 32k tile --------
    int bb = b - SC_B;
    int g = bb >> 7, rem = bb & 127;        // 128 tiles per gate
    const float* Wc; const float* Wl;
    if (g == 0)      { Wc = WcA; Wl = WlA; }
    else if (g == 1) { Wc = WcB; Wl = WlB; }
    else             { Wc = WcC; Wl = WlC; }
    int k0 = (rem & 15) * 32, j0 = (rem >> 4) * 64;
    int t = threadIdx.x;
    int tx = t & 7, ty = t >> 3;            // k-quad 0..7, j-pair 0..31
    float acc[2][4] = {};
    for (int c0 = 0; c0 < 512; c0 += 16) {
      if (t < 128) {                        // stage 32k x 16c of Wc
        int kk = t >> 2, c4 = (t & 3) * 4;
        f4 v = *(const f4*)(Wc + (size_t)(k0 + kk) * 512 + c0 + c4);
#pragma unroll
        for (int j = 0; j < 4; ++j) sWc[kk][c4 + j] = v[j];
      }
      { int cc = t >> 4, j4 = (t & 15) * 4; // stage 16c x 64j of Wl
        f4 v = *(const f4*)(Wl + (size_t)(c0 + cc) * 512 + j0 + j4);
        *(f4*)&sWl[cc][j4] = v; }
      __syncthreads();
#pragma unroll
      for (int cc = 0; cc < 16; ++cc) {
        float wcv[4], wlv[2];
#pragma unroll
        for (int q = 0; q < 4; ++q) wcv[q] = sWc[tx * 4 + q][cc];
#pragma unroll
        for (int a = 0; a < 2; ++a) wlv[a] = sWl[cc][ty * 2 + a];
#pragma unroll
        for (int a = 0; a < 2; ++a)
#pragma unroll
          for (int q = 0; q < 4; ++q) acc[a][q] += wlv[a] * wcv[q];
      }
      __syncthreads();
    }
#pragma unroll
    for (int a = 0; a < 2; ++a) {
      bf4v o;
#pragma unroll
      for (int q = 0; q < 4; ++q) o[q] = (bf16)acc[a][q];
      *(bf4v*)&Wt[((size_t)g * 512 + j0 + ty * 2 + a) * 512 + k0 + tx * 4] = o;
    }
  } else {
    // -------- bcomb[g][j] = bl_g[j] + sum_c bc_g[c]*Wl_g[c][j] --------
    int bb = b - SC_B - 384;
    int g = bb >> 3, jc = bb & 7;
    const float* bc; const float* bl; const float* Wl;
    if (g == 0)      { bc = bcA; bl = blA; Wl = WlA; }
    else if (g == 1) { bc = bcB; bl = blB; Wl = WlB; }
    else             { bc = bcC; bl = blC; Wl = WlC; }
    int jl = threadIdx.x & 63, part = threadIdx.x >> 6;
    int j = jc * 64 + jl;
    float s = 0.f;
    for (int c = part * 128; c < part * 128 + 128; ++c)
      s += bc[c] * Wl[(size_t)c * 512 + j];
    smr[part][jl] = s;
    __syncthreads();
    if (part == 0)
      bcomb[g * 512 + j] = bl[j] + smr[0][jl] + smr[1][jl] + smr[2][jl] + smr[3][jl];
  }
}

// ---------- gather-aggregate: one wave per dst node, 8-deep gather pipeline ----------
// 8 xbf rows in flight per wave; metadata (stream-once) via nontemporal s64 loads
// prefetched one group ahead; ybf written nontemporal (don't evict gather lines).
__global__ __launch_bounds__(256) void k_agg(const int2* __restrict__ off2, const long long* __restrict__ sn,
                                             const float* __restrict__ dinv, const bf16* __restrict__ xbf,
                                             bf16* __restrict__ ybf) {
  int wv = (blockIdx.x * 256 + threadIdx.x) >> 6;
  int lane = threadIdx.x & 63;
  if (wv >= MPAD) return;
  bf16* yrow = ybf + ((size_t)wv << 9) + lane * 8;
  if (wv >= NN) {
    bf8v z;
#pragma unroll
    for (int j = 0; j < 8; ++j) z[j] = (bf16)0.f;
    __builtin_nontemporal_store(z, (bf8v*)yrow);
    return;
  }
  float acc[8];
  float s0 = dinv[wv]; s0 *= s0;
  bf8v xv0 = *(const bf8v*)(xbf + ((size_t)wv << 9) + lane * 8);
#pragma unroll
  for (int j = 0; j < 8; ++j) acc[j] = s0 * (float)xv0[j];
  int2 seg = off2[wv];
  int e = seg.x, end = seg.y;
  long long m[8];
  bool have8 = (e + 8 <= end);
  if (have8) {
#pragma unroll
    for (int j = 0; j < 8; ++j) m[j] = __builtin_nontemporal_load(sn + e + j);
  }
  while (have8) {
    long long mn[8];
    bool next = (e + 16 <= end);
    if (next) {
#pragma unroll
      for (int j = 0; j < 8; ++j) mn[j] = __builtin_nontemporal_load(sn + e + 8 + j);
    }
    bf8v v[8];
#pragma unroll
    for (int j = 0; j < 8; ++j)
      v[j] = *(const bf8v*)(xbf + ((size_t)(int)(m[j] & 0xFFFFFFFFll) << 9) + lane * 8);
#pragma unroll
    for (int j = 0; j < 8; ++j) {
      float nrm = __int_as_float((int)(m[j] >> 32));
#pragma unroll
      for (int q = 0; q < 8; ++q) acc[q] += nrm * (float)v[j][q];
    }
    e += 8;
#pragma unroll
    for (int j = 0; j < 8; ++j) m[j] = mn[j];
    have8 = next;
  }
  for (; e < end; ++e) {
    long long p = __builtin_nontemporal_load(sn + e);
    bf8v v = *(const bf8v*)(xbf + ((size_t)(int)(p & 0xFFFFFFFFll) << 9) + lane * 8);
    float nn = __int_as_float((int)(p >> 32));
#pragma unroll
    for (int q = 0; q < 8; ++q) acc[q] += nn * (float)v[q];
  }
  bf8v o;
#pragma unroll
  for (int j = 0; j < 8; ++j) o[j] = (bf16)acc[j];
  __builtin_nontemporal_store(o, (bf8v*)yrow);
}

// ---------- main fused GEMM: BM=64, BK=32, 2x16KB LDS; counted-vmcnt pipeline ----------
// (R10-verified config: vmcnt(4) 2-deep, 64B-chunk swizzle, nontemporal epilogue stores.)
__global__ __launch_bounds__(256, 5) void k_gemm(const bf16* __restrict__ A, const bf16* __restrict__ Bt,
                                                 const float* __restrict__ bcomb, float* __restrict__ out) {
  __shared__ __align__(16) char lds[32768];  // 2 buffers x (A 4KB + B 3x4KB)
  const int t = threadIdx.x, lane = t & 63, w = t >> 6;
  const int wm = w >> 1, wn = w & 1;
  // XCD swizzle: 3760 = 8*470; consecutive s within an XCD share the A m-tile.
  const int d = blockIdx.x;
  const int s = (d & 7) * 470 + (d >> 3);
  const int m0 = (s >> 3) * 64, n0 = (s & 7) * 64;
  const int l15 = lane & 15, lhi = lane >> 4;
  f32x4 acc[3][2][2] = {};

  const int lq = lane >> 2;                        // row-within-16 for staging
  const int sw = (lane >> 3) & 3;                  // staging swizzle selector
  const int kcol = 16 * ((lane & 3) ^ sw);         // pre-swizzled src k-chunk byte
  const int rswz = 16 * (lhi ^ ((l15 >> 1) & 3));  // read-side swizzled chunk

  // loop-invariant staging source pointers (k advances via constant offset)
  const char* aS = (const char*)A + ((size_t)(m0 + w * 16 + lq) << 10) + kcol;
  const char* bS[3];
#pragma unroll
  for (int i = 0; i < 3; ++i) {
    int bi = i * 4 + w, g = bi >> 2, q = bi & 3;
    bS[i] = (const char*)Bt + ((size_t)(g * 512 + n0 + q * 16 + lq) << 10) + kcol;
  }
  // loop-invariant LDS read base offsets
  const int vA = (wm * 32 + l15) * 64 + rswz;         // within A region [0,4096)
  const int vB = 4096 + (wn * 32 + l15) * 64 + rswz;  // within B region [4096,16384)

  auto stage = [&](int bufoff, int kp) {
    gl_lds16(aS + kp * 64, lds + bufoff + w * 1024 + lane * 16);
#pragma unroll
    for (int i = 0; i < 3; ++i)
      gl_lds16(bS[i] + kp * 64, lds + bufoff + 4096 + (i * 4 + w) * 1024 + lane * 16);
  };

  auto compute = [&](int bufoff) {
    bf8v af[2];
#pragma unroll
    for (int mi = 0; mi < 2; ++mi)
      af[mi] = *(const bf8v*)(lds + bufoff + vA + mi * 1024);
#pragma unroll
    for (int g = 0; g < 3; ++g) {
      bf8v b0 = *(const bf8v*)(lds + bufoff + vB + g * 4096);
      bf8v b1 = *(const bf8v*)(lds + bufoff + vB + g * 4096 + 1024);
#pragma unroll
      for (int mi = 0; mi < 2; ++mi) {
        acc[g][mi][0] = __builtin_amdgcn_mfma_f32_16x16x32_bf16(b0, af[mi], acc[g][mi][0], 0, 0, 0);
        acc[g][mi][1] = __builtin_amdgcn_mfma_f32_16x16x32_bf16(b1, af[mi], acc[g][mi][1], 0, 0, 0);
      }
    }
  };

  // prologue: both buffers in flight (8 outstanding loads/wave)
  stage(0, 0);
  stage(16384, 1);
#pragma unroll
  for (int kp = 0; kp < 16; ++kp) {
    if (kp < 15) asm volatile("s_waitcnt vmcnt(4)" ::: "memory");
    else         asm volatile("s_waitcnt vmcnt(0)" ::: "memory");
    __builtin_amdgcn_sched_barrier(0);
    __builtin_amdgcn_s_barrier();           // buf[kp&1] ready for all waves
    __builtin_amdgcn_sched_barrier(0);
    compute((kp & 1) * 16384);
    __builtin_amdgcn_sched_barrier(0);
    __builtin_amdgcn_s_barrier();           // all waves done reading buf[kp&1]
    __builtin_amdgcn_sched_barrier(0);
    if (kp < 14) stage((kp & 1) * 16384, kp + 2);
  }

  // epilogue: gates + LSTM combine, nontemporal dwordx4 stores.
#pragma unroll
  for (int ni = 0; ni < 2; ++ni) {
    int nb = n0 + wn * 32 + ni * 16 + lhi * 4;
    f4 bI = *(const f4*)&bcomb[nb];
    f4 bG = *(const f4*)&bcomb[512 + nb];
    f4 bO = *(const f4*)&bcomb[1024 + nb];
#pragma unroll
    for (int mi = 0; mi < 2; ++mi) {
      int row = m0 + wm * 32 + mi * 16 + l15;
      if (row < NN) {
        f4 vO, vH, vC;
#pragma unroll
        for (int r = 0; r < 4; ++r) {
          float zi = acc[0][mi][ni][r] + bI[r];
          float zg = acc[1][mi][ni][r] + bG[r];
          float zo = acc[2][mi][ni][r] + bO[r];
          float I = 1.f / (1.f + __expf(-zi));
          float e2g = __expf(2.f * zg);
          float G = (e2g - 1.f) / (e2g + 1.f);
          float O = 1.f / (1.f + __expf(-zo));
          float Cn = I * G;
          float e2c = __expf(2.f * Cn);
          float tc = (e2c - 1.f) / (e2c + 1.f);
          vO[r] = O; vH[r] = O * tc; vC[r] = Cn;
        }
        size_t base = ((size_t)row << 9) + nb;
        __builtin_nontemporal_store(vO, (f4*)&out[base]);
        __builtin_nontemporal_store(vH, (f4*)&out[OUTSTRIDE + base]);
        __builtin_nontemporal_store(vC, (f4*)&out[2 * OUTSTRIDE + base]);
      }
    }
  }
}

extern "C" void kernel_launch(void* const* d_in, const int* in_sizes, int n_in,
                              void* d_out, int out_size, void* d_ws, size_t ws_size,
                              hipStream_t stream) {
  const float* x   = (const float*)d_in[0];
  const int*   ei  = (const int*)d_in[1];
  const float* ew  = (const float*)d_in[2];
  const float* Wc_i = (const float*)d_in[3];
  const float* bc_i = (const float*)d_in[4];
  const float* Wl_i = (const float*)d_in[5];
  const float* bl_i = (const float*)d_in[6];
  // F gate (d_in[7..10]) is dead: Cn = F*0 + I*G
  const float* Wc_g = (const float*)d_in[11];
  const float* bc_g = (const float*)d_in[12];
  const float* Wl_g = (const float*)d_in[13];
  const float* bl_g = (const float*)d_in[14];
  const float* Wc_o = (const float*)d_in[15];
  const float* bc_o = (const float*)d_in[16];
  const float* Wl_o = (const float*)d_in[17];
  const float* bl_o = (const float*)d_in[18];

  const int E = in_sizes[2];
  const int n = in_sizes[0] / 512;  // 30000
  const int NB = (n + 255) / 256;   // 118

  // workspace layout
  char* ws = (char*)d_ws;
  bf16*  ybf   = (bf16*)ws;                      // MPAD*512*2  = 30,801,920
  float* dinv  = (float*)(ws + 30801920);        // 120,000
  bf16*  Wt    = (bf16*)(ws + 30924800);         // 3*512*512*2 = 1,572,864
  float* bcomb = (float*)(ws + 32497664);        // 6,144
  (void)ws_size;

  // scratch inside d_out (184.3MB; all dead before k_gemm's epilogue writes)
  char* ob = (char*)d_out;
  float*  out    = (float*)d_out;
  bf16*   xbf    = (bf16*)ob;                  // [0, 30,720,000)
  int2*   sn     = (int2*)(ob + 30720000);     // 3,840,000 packed {src,norm}
  double* degcnt = (double*)(ob + 34560000);   // 240,000 packed {cnt*2^32 + sum(w)}
  int*    gctr   = (int*)(ob + 34800000);      // 64 (zeroed with degcnt)
  int*    curs   = (int*)(ob + 34800064);      // 120,000 (init by k_doffs)
  int2*   off2   = (int2*)(ob + 34920064);     // 240,000 {start, end}
  (void)out_size; (void)n_in;

  k_zero<<<(ZN16 + 255) / 256, 256, 0, stream>>>((f4*)degcnt);
  k_xp<<<XB + (E + 255) / 256, 256, 0, stream>>>(x, xbf, ei, ew, degcnt, E);
  k_doffs<<<NB, 256, 0, stream>>>(degcnt, dinv, gctr, curs, off2, n);
  k_fused<<<SC_B + 384 + 24, 256, 0, stream>>>(ei, ew, dinv, curs, sn, E,
                                               Wc_i, Wl_i, Wc_g, Wl_g, Wc_o, Wl_o, Wt,
                                               bc_i, bl_i, bc_g, bl_g, bc_o, bl_o, bcomb);
  k_agg<<<(MPAD * 64 + 255) / 256, 256, 0, stream>>>(off2, (const long long*)sn, dinv, xbf, ybf);
  k_gemm<<<3760, 256, 0, stream>>>(ybf, Wt, bcomb, out);
}

// Round 16
// 273.408 us; speedup vs baseline: 1.0931x; 1.0931x over previous
//
#include <hip/hip_runtime.h>
#include <stdint.h>

typedef __bf16 bf16;
typedef __attribute__((ext_vector_type(4))) float f4;
typedef __attribute__((ext_vector_type(4))) float f32x4;
typedef __attribute__((ext_vector_type(8))) __bf16 bf8v;
typedef __attribute__((ext_vector_type(4))) __bf16 bf4v;

#define NN 30000
#define MPAD 30080
#define OUTSTRIDE 15360000     // 30000*512
#define XB 7500                // cast blocks in k_xp (1920000/256)
#define SC_B 1875              // scatter blocks in k_fused (480000/256)
#define TWO32 4294967296.0
#define ZN16 15004             // 240064 bytes / 16 (degcnt + gctr)

typedef __attribute__((address_space(3))) unsigned int as3_u32;
typedef __attribute__((address_space(1))) unsigned int as1_u32;

__device__ __forceinline__ void gl_lds16(const void* g, void* l) {
  __builtin_amdgcn_global_load_lds((as1_u32*)g, (as3_u32*)l, 16, 0, 0);
}

// ---------- zero {degcnt, gctr} ----------
__global__ void k_zero(f4* __restrict__ p) {
  int i = blockIdx.x * 256 + threadIdx.x;
  if (i < ZN16) { f4 z = {0.f, 0.f, 0.f, 0.f}; p[i] = z; }
}

// ---------- fused: x->bf16 cast + per-edge degree/count accumulation ----------
// degcnt[d] (double) accumulates ew + 2^32 (count in upper bits, weight-sum in lower).
__global__ void k_xp(const float* __restrict__ x, bf16* __restrict__ xbf,
                     const int* __restrict__ ei, const float* __restrict__ ew,
                     double* __restrict__ degcnt, int E) {
  int b = blockIdx.x;
  if (b < XB) {
    int i = b * 256 + threadIdx.x;
    const f4* x4 = (const f4*)x;
    f4 a = x4[2 * i], c = x4[2 * i + 1];
    bf8v o;
#pragma unroll
    for (int j = 0; j < 4; ++j) { o[j] = (bf16)a[j]; o[4 + j] = (bf16)c[j]; }
    ((bf8v*)xbf)[i] = o;
  } else {
    int e = (b - XB) * 256 + threadIdx.x;
    if (e < E) {
      int d = ei[E + e];
      atomicAdd(&degcnt[d], (double)ew[e] + TWO32);
    }
  }
}

// ---------- dinv + atomic CSR offset allocation; curs pre-set to start ----------
__global__ void k_doffs(const double* __restrict__ degcnt, float* __restrict__ dinv,
                        int* __restrict__ gctr, int* __restrict__ curs,
                        int2* __restrict__ off2, int n) {
  int i = blockIdx.x * 256 + threadIdx.x;
  if (i >= n) return;
  double v = degcnt[i];
  double c = (double)(long long)(v * (1.0 / TWO32));  // exact count
  int cnt = (int)c;
  float deg = (float)(v - c * TWO32);
  dinv[i] = rsqrtf(deg + 1.0f);  // +1 = self-loop weight
  int start = atomicAdd(gctr, cnt);
  curs[i] = start;                    // scatter cursor starts at segment base
  off2[i] = make_int2(start, start + cnt);
}

// ---------- fused: scatter (CSR build, cursor-only) + W_comb (64j x 32k) + bias ----------
__global__ void k_fused(const int* __restrict__ ei, const float* __restrict__ ew,
                        const float* __restrict__ dinv,
                        int* __restrict__ cursor, int2* __restrict__ sn, int E,
                        const float* __restrict__ WcA, const float* __restrict__ WlA,
                        const float* __restrict__ WcB, const float* __restrict__ WlB,
                        const float* __restrict__ WcC, const float* __restrict__ WlC,
                        bf16* __restrict__ Wt,
                        const float* __restrict__ bcA, const float* __restrict__ blA,
                        const float* __restrict__ bcB, const float* __restrict__ blB,
                        const float* __restrict__ bcC, const float* __restrict__ blC,
                        float* __restrict__ bcomb) {
  __shared__ float sWc[32][17];   // [k][c] chunk
  __shared__ float sWl[16][64];   // [c][j] chunk
  __shared__ float smr[4][64];
  int b = blockIdx.x;
  if (b < SC_B) {
    // -------- scatter edges into CSR-by-dst (packed {src, norm}) --------
    int e = b * 256 + threadIdx.x;
    if (e >= E) return;
    int s = ei[e], d = ei[E + e];
    int pos = atomicAdd(&cursor[d], 1);
    sn[pos] = make_int2(s, __float_as_int(dinv[s] * ew[e] * dinv[d]));
  } else if (b < SC_B + 384) {
    // -------- Wt[g][j][k] = sum_c Wc_g[k][c] * Wl_g[c][j], 64j x 32k tile --------
    int bb = b - SC_B;
    int g = bb >> 7, rem = bb & 127;        // 128 tiles per gate
    const float* Wc; const float* Wl;
    if (g == 0)      { Wc = WcA; Wl = WlA; }
    else if (g == 1) { Wc = WcB; Wl = WlB; }
    else             { Wc = WcC; Wl = WlC; }
    int k0 = (rem & 15) * 32, j0 = (rem >> 4) * 64;
    int t = threadIdx.x;
    int tx = t & 7, ty = t >> 3;            // k-quad 0..7, j-pair 0..31
    float acc[2][4] = {};
    for (int c0 = 0; c0 < 512; c0 += 16) {
      if (t < 128) {                        // stage 32k x 16c of Wc
        int kk = t >> 2, c4 = (t & 3) * 4;
        f4 v = *(const f4*)(Wc + (size_t)(k0 + kk) * 512 + c0 + c4);
#pragma unroll
        for (int j = 0; j < 4; ++j) sWc[kk][c4 + j] = v[j];
      }
      { int cc = t >> 4, j4 = (t & 15) * 4; // stage 16c x 64j of Wl
        f4 v = *(const f4*)(Wl + (size_t)(c0 + cc) * 512 + j0 + j4);
        *(f4*)&sWl[cc][j4] = v; }
      __syncthreads();
#pragma unroll
      for (int cc = 0; cc < 16; ++cc) {
        float wcv[4], wlv[2];
#pragma unroll
        for (int q = 0; q < 4; ++q) wcv[q] = sWc[tx * 4 + q][cc];
#pragma unroll
        for (int a = 0; a < 2; ++a) wlv[a] = sWl[cc][ty * 2 + a];
#pragma unroll
        for (int a = 0; a < 2; ++a)
#pragma unroll
          for (int q = 0; q < 4; ++q) acc[a][q] += wlv[a] * wcv[q];
      }
      __syncthreads();
    }
#pragma unroll
    for (int a = 0; a < 2; ++a) {
      bf4v o;
#pragma unroll
      for (int q = 0; q < 4; ++q) o[q] = (bf16)acc[a][q];
      *(bf4v*)&Wt[((size_t)g * 512 + j0 + ty * 2 + a) * 512 + k0 + tx * 4] = o;
    }
  } else {
    // -------- bcomb[g][j] = bl_g[j] + sum_c bc_g[c]*Wl_g[c][j] --------
    int bb = b - SC_B - 384;
    int g = bb >> 3, jc = bb & 7;
    const float* bc; const float* bl; const float* Wl;
    if (g == 0)      { bc = bcA; bl = blA; Wl = WlA; }
    else if (g == 1) { bc = bcB; bl = blB; Wl = WlB; }
    else             { bc = bcC; bl = blC; Wl = WlC; }
    int jl = threadIdx.x & 63, part = threadIdx.x >> 6;
    int j = jc * 64 + jl;
    float s = 0.f;
    for (int c = part * 128; c < part * 128 + 128; ++c)
      s += bc[c] * Wl[(size_t)c * 512 + j];
    smr[part][jl] = s;
    __syncthreads();
    if (part == 0)
      bcomb[g * 512 + j] = bl[j] + smr[0][jl] + smr[1][jl] + smr[2][jl] + smr[3][jl];
  }
}

// ---------- gather-aggregate: one wave per dst node, sn-prefetch pipelined ----------
// (273.6us-verified form: int2 metadata, 4-deep, REGULAR stores — ybf must stay
// cache-resident for k_gemm's A staging; nt stores here cost k_gemm +20us (R15).)
__global__ __launch_bounds__(256) void k_agg(const int2* __restrict__ off2, const int2* __restrict__ sn,
                                             const float* __restrict__ dinv, const bf16* __restrict__ xbf,
                                             bf16* __restrict__ ybf) {
  int wv = (blockIdx.x * 256 + threadIdx.x) >> 6;
  int lane = threadIdx.x & 63;
  if (wv >= MPAD) return;
  bf16* yrow = ybf + ((size_t)wv << 9) + lane * 8;
  if (wv >= NN) {
    bf8v z;
#pragma unroll
    for (int j = 0; j < 8; ++j) z[j] = (bf16)0.f;
    *(bf8v*)yrow = z;
    return;
  }
  float acc[8];
  float s0 = dinv[wv]; s0 *= s0;
  bf8v xv0 = *(const bf8v*)(xbf + ((size_t)wv << 9) + lane * 8);
#pragma unroll
  for (int j = 0; j < 8; ++j) acc[j] = s0 * (float)xv0[j];
  int2 seg = off2[wv];
  int e = seg.x, end = seg.y;
  int2 p0, p1, p2, p3;
  const bool have = (e + 4 <= end);
  if (have) { p0 = sn[e]; p1 = sn[e + 1]; p2 = sn[e + 2]; p3 = sn[e + 3]; }
  for (; e + 8 <= end; e += 4) {
    int2 q0 = sn[e + 4], q1 = sn[e + 5], q2 = sn[e + 6], q3 = sn[e + 7];
    bf8v v0 = *(const bf8v*)(xbf + ((size_t)p0.x << 9) + lane * 8);
    bf8v v1 = *(const bf8v*)(xbf + ((size_t)p1.x << 9) + lane * 8);
    bf8v v2 = *(const bf8v*)(xbf + ((size_t)p2.x << 9) + lane * 8);
    bf8v v3 = *(const bf8v*)(xbf + ((size_t)p3.x << 9) + lane * 8);
    float n0 = __int_as_float(p0.y), n1 = __int_as_float(p1.y);
    float n2 = __int_as_float(p2.y), n3 = __int_as_float(p3.y);
#pragma unroll
    for (int j = 0; j < 8; ++j)
      acc[j] += n0 * (float)v0[j] + n1 * (float)v1[j] + n2 * (float)v2[j] + n3 * (float)v3[j];
    p0 = q0; p1 = q1; p2 = q2; p3 = q3;
  }
  if (have) {
    bf8v v0 = *(const bf8v*)(xbf + ((size_t)p0.x << 9) + lane * 8);
    bf8v v1 = *(const bf8v*)(xbf + ((size_t)p1.x << 9) + lane * 8);
    bf8v v2 = *(const bf8v*)(xbf + ((size_t)p2.x << 9) + lane * 8);
    bf8v v3 = *(const bf8v*)(xbf + ((size_t)p3.x << 9) + lane * 8);
    float n0 = __int_as_float(p0.y), n1 = __int_as_float(p1.y);
    float n2 = __int_as_float(p2.y), n3 = __int_as_float(p3.y);
#pragma unroll
    for (int j = 0; j < 8; ++j)
      acc[j] += n0 * (float)v0[j] + n1 * (float)v1[j] + n2 * (float)v2[j] + n3 * (float)v3[j];
    e += 4;
  }
  for (; e < end; ++e) {
    int2 p = sn[e];
    bf8v v = *(const bf8v*)(xbf + ((size_t)p.x << 9) + lane * 8);
    float nn = __int_as_float(p.y);
#pragma unroll
    for (int j = 0; j < 8; ++j) acc[j] += nn * (float)v[j];
  }
  bf8v o;
#pragma unroll
  for (int j = 0; j < 8; ++j) o[j] = (bf16)acc[j];
  *(bf8v*)yrow = o;
}

// ---------- main fused GEMM: BM=64, BK=32, 2x16KB LDS; counted-vmcnt pipeline ----------
// (R10-verified config: vmcnt(4) 2-deep, 64B-chunk swizzle, nontemporal epilogue stores.)
__global__ __launch_bounds__(256, 5) void k_gemm(const bf16* __restrict__ A, const bf16* __restrict__ Bt,
                                                 const float* __restrict__ bcomb, float* __restrict__ out) {
  __shared__ __align__(16) char lds[32768];  // 2 buffers x (A 4KB + B 3x4KB)
  const int t = threadIdx.x, lane = t & 63, w = t >> 6;
  const int wm = w >> 1, wn = w & 1;
  // XCD swizzle: 3760 = 8*470; consecutive s within an XCD share the A m-tile.
  const int d = blockIdx.x;
  const int s = (d & 7) * 470 + (d >> 3);
  const int m0 = (s >> 3) * 64, n0 = (s & 7) * 64;
  const int l15 = lane & 15, lhi = lane >> 4;
  f32x4 acc[3][2][2] = {};

  const int lq = lane >> 2;                        // row-within-16 for staging
  const int sw = (lane >> 3) & 3;                  // staging swizzle selector
  const int kcol = 16 * ((lane & 3) ^ sw);         // pre-swizzled src k-chunk byte
  const int rswz = 16 * (lhi ^ ((l15 >> 1) & 3));  // read-side swizzled chunk

  // loop-invariant staging source pointers (k advances via constant offset)
  const char* aS = (const char*)A + ((size_t)(m0 + w * 16 + lq) << 10) + kcol;
  const char* bS[3];
#pragma unroll
  for (int i = 0; i < 3; ++i) {
    int bi = i * 4 + w, g = bi >> 2, q = bi & 3;
    bS[i] = (const char*)Bt + ((size_t)(g * 512 + n0 + q * 16 + lq) << 10) + kcol;
  }
  // loop-invariant LDS read base offsets
  const int vA = (wm * 32 + l15) * 64 + rswz;         // within A region [0,4096)
  const int vB = 4096 + (wn * 32 + l15) * 64 + rswz;  // within B region [4096,16384)

  auto stage = [&](int bufoff, int kp) {
    gl_lds16(aS + kp * 64, lds + bufoff + w * 1024 + lane * 16);
#pragma unroll
    for (int i = 0; i < 3; ++i)
      gl_lds16(bS[i] + kp * 64, lds + bufoff + 4096 + (i * 4 + w) * 1024 + lane * 16);
  };

  auto compute = [&](int bufoff) {
    bf8v af[2];
#pragma unroll
    for (int mi = 0; mi < 2; ++mi)
      af[mi] = *(const bf8v*)(lds + bufoff + vA + mi * 1024);
#pragma unroll
    for (int g = 0; g < 3; ++g) {
      bf8v b0 = *(const bf8v*)(lds + bufoff + vB + g * 4096);
      bf8v b1 = *(const bf8v*)(lds + bufoff + vB + g * 4096 + 1024);
#pragma unroll
      for (int mi = 0; mi < 2; ++mi) {
        acc[g][mi][0] = __builtin_amdgcn_mfma_f32_16x16x32_bf16(b0, af[mi], acc[g][mi][0], 0, 0, 0);
        acc[g][mi][1] = __builtin_amdgcn_mfma_f32_16x16x32_bf16(b1, af[mi], acc[g][mi][1], 0, 0, 0);
      }
    }
  };

  // prologue: both buffers in flight (8 outstanding loads/wave)
  stage(0, 0);
  stage(16384, 1);
#pragma unroll
  for (int kp = 0; kp < 16; ++kp) {
    if (kp < 15) asm volatile("s_waitcnt vmcnt(4)" ::: "memory");
    else         asm volatile("s_waitcnt vmcnt(0)" ::: "memory");
    __builtin_amdgcn_sched_barrier(0);
    __builtin_amdgcn_s_barrier();           // buf[kp&1] ready for all waves
    __builtin_amdgcn_sched_barrier(0);
    compute((kp & 1) * 16384);
    __builtin_amdgcn_sched_barrier(0);
    __builtin_amdgcn_s_barrier();           // all waves done reading buf[kp&1]
    __builtin_amdgcn_sched_barrier(0);
    if (kp < 14) stage((kp & 1) * 16384, kp + 2);
  }

  // epilogue: gates + LSTM combine, nontemporal dwordx4 stores (out is write-once).
#pragma unroll
  for (int ni = 0; ni < 2; ++ni) {
    int nb = n0 + wn * 32 + ni * 16 + lhi * 4;
    f4 bI = *(const f4*)&bcomb[nb];
    f4 bG = *(const f4*)&bcomb[512 + nb];
    f4 bO = *(const f4*)&bcomb[1024 + nb];
#pragma unroll
    for (int mi = 0; mi < 2; ++mi) {
      int row = m0 + wm * 32 + mi * 16 + l15;
      if (row < NN) {
        f4 vO, vH, vC;
#pragma unroll
        for (int r = 0; r < 4; ++r) {
          float zi = acc[0][mi][ni][r] + bI[r];
          float zg = acc[1][mi][ni][r] + bG[r];
          float zo = acc[2][mi][ni][r] + bO[r];
          float I = 1.f / (1.f + __expf(-zi));
          float e2g = __expf(2.f * zg);
          float G = (e2g - 1.f) / (e2g + 1.f);
          float O = 1.f / (1.f + __expf(-zo));
          float Cn = I * G;
          float e2c = __expf(2.f * Cn);
          float tc = (e2c - 1.f) / (e2c + 1.f);
          vO[r] = O; vH[r] = O * tc; vC[r] = Cn;
        }
        size_t base = ((size_t)row << 9) + nb;
        __builtin_nontemporal_store(vO, (f4*)&out[base]);
        __builtin_nontemporal_store(vH, (f4*)&out[OUTSTRIDE + base]);
        __builtin_nontemporal_store(vC, (f4*)&out[2 * OUTSTRIDE + base]);
      }
    }
  }
}

extern "C" void kernel_launch(void* const* d_in, const int* in_sizes, int n_in,
                              void* d_out, int out_size, void* d_ws, size_t ws_size,
                              hipStream_t stream) {
  const float* x   = (const float*)d_in[0];
  const int*   ei  = (const int*)d_in[1];
  const float* ew  = (const float*)d_in[2];
  const float* Wc_i = (const float*)d_in[3];
  const float* bc_i = (const float*)d_in[4];
  const float* Wl_i = (const float*)d_in[5];
  const float* bl_i = (const float*)d_in[6];
  // F gate (d_in[7..10]) is dead: Cn = F*0 + I*G
  const float* Wc_g = (const float*)d_in[11];
  const float* bc_g = (const float*)d_in[12];
  const float* Wl_g = (const float*)d_in[13];
  const float* bl_g = (const float*)d_in[14];
  const float* Wc_o = (const float*)d_in[15];
  const float* bc_o = (const float*)d_in[16];
  const float* Wl_o = (const float*)d_in[17];
  const float* bl_o = (const float*)d_in[18];

  const int E = in_sizes[2];
  const int n = in_sizes[0] / 512;  // 30000
  const int NB = (n + 255) / 256;   // 118

  // workspace layout
  char* ws = (char*)d_ws;
  bf16*  ybf   = (bf16*)ws;                      // MPAD*512*2  = 30,801,920
  float* dinv  = (float*)(ws + 30801920);        // 120,000
  bf16*  Wt    = (bf16*)(ws + 30924800);         // 3*512*512*2 = 1,572,864
  float* bcomb = (float*)(ws + 32497664);        // 6,144
  (void)ws_size;

  // scratch inside d_out (184.3MB; all dead before k_gemm's epilogue writes)
  char* ob = (char*)d_out;
  float*  out    = (float*)d_out;
  bf16*   xbf    = (bf16*)ob;                  // [0, 30,720,000)
  int2*   sn     = (int2*)(ob + 30720000);     // 3,840,000 packed {src,norm}
  double* degcnt = (double*)(ob + 34560000);   // 240,000 packed {cnt*2^32 + sum(w)}
  int*    gctr   = (int*)(ob + 34800000);      // 64 (zeroed with degcnt)
  int*    curs   = (int*)(ob + 34800064);      // 120,000 (init by k_doffs)
  int2*   off2   = (int2*)(ob + 34920064);     // 240,000 {start, end}
  (void)out_size; (void)n_in;

  k_zero<<<(ZN16 + 255) / 256, 256, 0, stream>>>((f4*)degcnt);
  k_xp<<<XB + (E + 255) / 256, 256, 0, stream>>>(x, xbf, ei, ew, degcnt, E);
  k_doffs<<<NB, 256, 0, stream>>>(degcnt, dinv, gctr, curs, off2, n);
  k_fused<<<SC_B + 384 + 24, 256, 0, stream>>>(ei, ew, dinv, curs, sn, E,
                                               Wc_i, Wl_i, Wc_g, Wl_g, Wc_o, Wl_o, Wt,
                                               bc_i, bl_i, bc_g, bl_g, bc_o, bl_o, bcomb);
  k_agg<<<(MPAD * 64 + 255) / 256, 256, 0, stream>>>(off2, sn, dinv, xbf, ybf);
  k_gemm<<<3760, 256, 0, stream>>>(ybf, Wt, bcomb, out);
}